// Round 10
// baseline (55.390 us; speedup 1.0000x reference)
//
#include <hip/hip_runtime.h>

#define BATCH   1024
#define NF      64
#define EDIM    64
#define ADIM    32
#define NPAIR   2016        // 64*63/2
#define XSTR    72          // f16 elems/row: 144B rows -> 16B aligned, bank rot 4/row
#define ASTR    68          // As stride: 136B rows -> 8B aligned (b64 reads), 4-way col scatter

typedef _Float16 f16;
typedef f16   f16x2  __attribute__((ext_vector_type(2)));
typedef f16   f16x4  __attribute__((ext_vector_type(4)));
typedef f16   f16x8  __attribute__((ext_vector_type(8)));
typedef float f32x2  __attribute__((ext_vector_type(2)));
typedef float f32x4  __attribute__((ext_vector_type(4)));
typedef float f32x16 __attribute__((ext_vector_type(16)));

__device__ __forceinline__ f16x8 asH(int4 v) {
    union { int4 i; f16x8 h; } u; u.i = v; return u.h;
}
__device__ __forceinline__ f16x2 pkrtz(float a, float b) {
    union { __fp16 __attribute__((ext_vector_type(2))) r; f16x2 h; } u;
    u.r = __builtin_amdgcn_cvt_pkrtz(a, b);
    return u.h;
}

__global__ __launch_bounds__(256, 5) void afm_kernel(
    const float* __restrict__ emb,    // (B, NF, E)
    const float* __restrict__ W1,     // (E, A)
    const float* __restrict__ b1,     // (A)
    const float* __restrict__ W2,     // (A, 1)
    const float* __restrict__ b2,     // (1)
    float* __restrict__ out_vec,      // (B, E)
    float* __restrict__ out_attn)     // (B, NPAIR)
{
    __shared__ __align__(16) f16 xs[NF * XSTR];   // x, f16, [field][e]
    __shared__ __align__(16) f16 Xt[EDIM * XSTR]; // x^T, f16, [e][field]
    __shared__ __align__(16) f16 As[NF * ASTR];   // UNNORMALIZED exp matrix, f16
    // eh: unnormalized exp values (f16, p-indexed, 4032 B). partial (1024 B)
    // aliases its start: all eh reads finish before the red-barrier; partial
    // is written only after it.
    __shared__ __align__(16) char Ubuf[NPAIR * 2];
    f16* eh = (f16*)Ubuf;
    float (*partial)[EDIM] = (float (*)[EDIM])Ubuf;
    __shared__ float red[8];

    const int t    = threadIdx.x;
    const int b    = blockIdx.x;
    const int wid  = t >> 6;
    const int lane = t & 63;
    const int g    = lane >> 4;   // for phase 3 (16x16 fragments)
    const int m16  = lane & 15;
    const int h    = lane >> 5;   // K-half for 32x32 fragments
    const int l32  = lane & 31;
    const int l16  = lane & 15;
    const int hb   = l32 >> 4;    // 16-row within 32-col group

    // ---- stage x into LDS as f16 (row-major; transpose built later) ----
    const float4* xg4 = (const float4*)(emb + (size_t)b * NF * EDIM);
    #pragma unroll
    for (int it = 0; it < 4; ++it) {
        int idx = t + it * 256;
        int f = idx >> 4, e4 = (idx & 15) * 4;
        float4 v = xg4[idx];
        f16x2 p0 = pkrtz(v.x, v.y);
        f16x2 p1 = pkrtz(v.z, v.w);
        f16x4 pk = {p0.x, p0.y, p1.x, p1.y};
        *(f16x4*)&xs[f * XSTR + e4] = pk;
    }

    // ---- W1^T A-fragments for 32x32x16: A[m=adim=l32][k=8h+jj] ----
    f16x8 w1a[4];
    #pragma unroll
    for (int q = 0; q < 4; ++q)
        #pragma unroll
        for (int jj = 0; jj < 8; jj += 2) {
            float fa = W1[(16 * q + 8 * h + jj)     * ADIM + l32];
            float fb = W1[(16 * q + 8 * h + jj + 1) * ADIM + l32];
            f16x2 pk = pkrtz(fa, fb);
            w1a[q][jj] = pk.x; w1a[q][jj + 1] = pk.y;
        }

    // b1/W2 as packed f32x2 pairs in C/D row order: a(r) = (r&3)+8*(r>>2)+4h
    f32x2 b1f2[8], w2f2[8];
    #pragma unroll
    for (int rr = 0; rr < 8; ++rr) {
        int r = 2 * rr;
        int a = (r & 3) + 8 * (r >> 2) + 4 * h;
        b1f2[rr] = (f32x2){b1[a], b1[a + 1]};
        w2f2[rr] = (f32x2){W2[a], W2[a + 1]};
    }
    const float b2s = b2[0];
    __syncthreads();

    // ---- build Xt via read-transpose (no barrier needed after: phase 1 reads
    // only xs; Xt's first read (phase 3) is separated by later barriers) ----
    {
        const unsigned short* xsu = (const unsigned short*)xs;
        #pragma unroll
        for (int it = 0; it < 2; ++it) {
            int cid = t + it * 256;
            int e = cid & 63, c = cid >> 6;     // e = lane, c uniform per wave
            unsigned int d[4];
            #pragma unroll
            for (int r2 = 0; r2 < 4; ++r2) {
                unsigned lo = xsu[(8 * c + 2 * r2)     * XSTR + e];
                unsigned hi = xsu[(8 * c + 2 * r2 + 1) * XSTR + e];
                d[r2] = lo | (hi << 16);
            }
            int4 w4 = {(int)d[0], (int)d[1], (int)d[2], (int)d[3]};
            *(int4*)&Xt[e * XSTR + 8 * c] = w4;
        }
    }

    // ---- DPP direction probe: jv registers rotate WITH the data ----
    int probe = __builtin_amdgcn_mov_dpp(l16, 0x124, 0xF, 0xF, false);
    const bool plus4 = (probe == ((l16 + 4) & 15));
    const int  s0r   = plus4 ? (wid + 1) : (wid + 5);

    // ---- phase 1: exp(logit) via 32x32x16 MFMA, register rows + DPP ----
    int4 xi4[4], xj4[4];

    auto LOADX = [&](int row, int4* d) {
        #pragma unroll
        for (int q = 0; q < 4; ++q)
            d[q] = *(const int4*)&xs[row * XSTR + 16 * q + 8 * h];
    };
    auto ROT4D = [&](int4* d, int& jv) {   // rotate data AND its row index
        #pragma unroll
        for (int q = 0; q < 4; ++q) {
            d[q].x = __builtin_amdgcn_mov_dpp(d[q].x, 0x124, 0xF, 0xF, false);
            d[q].y = __builtin_amdgcn_mov_dpp(d[q].y, 0x124, 0xF, 0xF, false);
            d[q].z = __builtin_amdgcn_mov_dpp(d[q].z, 0x124, 0xF, 0xF, false);
            d[q].w = __builtin_amdgcn_mov_dpp(d[q].w, 0x124, 0xF, 0xF, false);
        }
        jv = __builtin_amdgcn_mov_dpp(jv, 0x124, 0xF, 0xF, false);
    };
    auto SUB = [&](const int4* xa, const int4* xb, int iv, int jv) {
        f32x16 acc = {};
        #pragma unroll
        for (int q = 0; q < 4; ++q) {
            f16x8 prod = asH(xa[q]) * asH(xb[q]);   // v_pk_mul_f16 x4
            acc = __builtin_amdgcn_mfma_f32_32x32x16_f16(w1a[q], prod, acc, 0, 0, 0);
        }
        f32x2 tr2 = {0.f, 0.f};
        #pragma unroll
        for (int rr = 0; rr < 8; ++rr) {
            f32x2 a2 = {acc[2 * rr], acc[2 * rr + 1]};
            f32x2 h2 = __builtin_elementwise_max(a2 + b1f2[rr], (f32x2){0.f, 0.f});
            tr2 += h2 * w2f2[rr];
        }
        float tr = tr2.x + tr2.y;
        tr += __shfl_xor(tr, 32);
        // Unnormalized softmax numerator; logits bounded (~|5|) so exp fits
        // f16 (max 65504) with huge headroom. Normalization folded later.
        float ev = __expf(tr + b2s);
        int imin = min(iv, jv), jmax = max(iv, jv);
        int p = ((imin * (127 - imin)) >> 1) + jmax - imin - 1;
        if (lane < 32) {
            f16 ah = (f16)ev;
            eh[p] = ah;
            As[imin * ASTR + jmax] = ah;
            As[jmax * ASTR + imin] = ah;
        }
    };

    LOADX(l32, xi4);
    {   // off-diag (0,1) pattern A
        int jv = 32 + 16 * hb + ((l16 + wid) & 15);
        LOADX(jv, xj4);
        #pragma unroll
        for (int k = 0; k < 4; ++k) {
            SUB(xi4, xj4, l32, jv);
            if (k < 3) ROT4D(xj4, jv);
        }
    }
    {   // off-diag (0,1) pattern B
        int jv = 32 + 16 * (1 - hb) + ((l16 + wid) & 15);
        LOADX(jv, xj4);
        #pragma unroll
        for (int k = 0; k < 4; ++k) {
            SUB(xi4, xj4, l32, jv);
            if (k < 3) ROT4D(xj4, jv);
        }
    }
    {   // diag (0,0) ring
        int jv = 16 * hb + ((l16 + s0r) & 15);
        LOADX(jv, xj4);
        SUB(xi4, xj4, l32, jv);
        ROT4D(xj4, jv);
        SUB(xi4, xj4, l32, jv);
    }
    {   // diag (0,0) cross
        int jv = 16 + ((l16 + wid + 8 * hb) & 15);
        LOADX(l16, xi4);
        LOADX(jv, xj4);
        SUB(xi4, xj4, l16, jv);
        ROT4D(xj4, jv);
        SUB(xi4, xj4, l16, jv);
    }
    {   // diag (1,1) ring
        int jv = 32 + 16 * hb + ((l16 + s0r) & 15);
        LOADX(32 + l32, xi4);
        LOADX(jv, xj4);
        SUB(xi4, xj4, 32 + l32, jv);
        ROT4D(xj4, jv);
        SUB(xi4, xj4, 32 + l32, jv);
    }
    {   // diag (1,1) cross
        int jv = 48 + ((l16 + wid + 8 * hb) & 15);
        LOADX(32 + l16, xi4);
        LOADX(jv, xj4);
        SUB(xi4, xj4, 32 + l16, jv);
        ROT4D(xj4, jv);
        SUB(xi4, xj4, 32 + l16, jv);
    }
    if (t < NF) As[t * ASTR + t] = (f16)0.f;   // zero diagonal (i != j in SUBs)
    __syncthreads();

    // ---- phase 2: SUM reduction over f16 exp values ----
    float lv[8];
    #pragma unroll
    for (int k = 0; k < 8; ++k) {
        int p = t + 256 * k;
        lv[k] = (p < NPAIR) ? (float)eh[p] : 0.f;
    }
    float sw = 0.f;
    #pragma unroll
    for (int k = 0; k < 8; ++k) sw += lv[k];
    #pragma unroll
    for (int off = 32; off; off >>= 1) sw += __shfl_xor(sw, off);
    if (lane == 0) red[wid] = sw;
    __syncthreads();      // after this barrier eh is dead; partial may alias
    const float inv = 1.0f / (red[0] + red[1] + red[2] + red[3]);

    #pragma unroll
    for (int k = 0; k < 8; ++k) {
        int p = t + 256 * k;
        if (p < NPAIR) out_attn[(size_t)b * NPAIR + p] = lv[k] * inv;
    }

    // ---- phase 3: Y = E @ X via MFMA; out[e] = 0.5*inv * sum_i X[i,e] Y[i,e] ----
    const int itile = wid;          // each wave owns 16 rows of E
    const f16* arow = &As[(itile * 16 + m16) * ASTR];
    f16x4 afa0 = *(const f16x4*)(arow + 8 * g);
    f16x4 afb0 = *(const f16x4*)(arow + 8 * g + 4);
    f16x4 afa1 = *(const f16x4*)(arow + 32 + 8 * g);
    f16x4 afb1 = *(const f16x4*)(arow + 32 + 8 * g + 4);
    f16x8 af0, af1;
    #pragma unroll
    for (int j = 0; j < 4; ++j) {
        af0[j] = afa0[j]; af0[4 + j] = afb0[j];
        af1[j] = afa1[j]; af1[4 + j] = afb1[j];
    }

    f32x4 yacc[4];
    #pragma unroll
    for (int et = 0; et < 4; ++et) yacc[et] = (f32x4){0.f, 0.f, 0.f, 0.f};
    #pragma unroll
    for (int et = 0; et < 4; ++et) {
        const f16* xtr = &Xt[(et * 16 + m16) * XSTR];
        f16x8 bf0 = *(const f16x8*)(xtr + 8 * g);
        f16x8 bf1 = *(const f16x8*)(xtr + 32 + 8 * g);
        yacc[et] = __builtin_amdgcn_mfma_f32_16x16x32_f16(af0, bf0, yacc[et], 0, 0, 0);
        yacc[et] = __builtin_amdgcn_mfma_f32_16x16x32_f16(af1, bf1, yacc[et], 0, 0, 0);
    }

    #pragma unroll
    for (int et = 0; et < 4; ++et) {
        float v = 0.f;
        #pragma unroll
        for (int r = 0; r < 4; ++r) {
            int i = itile * 16 + 4 * g + r;
            int e = et * 16 + m16;
            v = fmaf((float)xs[i * XSTR + e], yacc[et][r], v);
        }
        v += __shfl_xor(v, 16);
        v += __shfl_xor(v, 32);
        if (g == 0) partial[wid][et * 16 + m16] = v;
    }
    __syncthreads();
    if (t < EDIM)
        out_vec[(size_t)b * EDIM + t] = 0.5f * inv *
            (partial[0][t] + partial[1][t] + partial[2][t] + partial[3][t]);
}

extern "C" void kernel_launch(void* const* d_in, const int* in_sizes, int n_in,
                              void* d_out, int out_size, void* d_ws, size_t ws_size,
                              hipStream_t stream) {
    const float* emb = (const float*)d_in[0];
    const float* W1  = (const float*)d_in[1];
    const float* b1  = (const float*)d_in[2];
    const float* W2  = (const float*)d_in[3];
    const float* b2  = (const float*)d_in[4];
    float* out_vec  = (float*)d_out;                        // (B, E)
    float* out_attn = (float*)d_out + (size_t)BATCH * EDIM; // (B, NPAIR)

    afm_kernel<<<BATCH, 256, 0, stream>>>(emb, W1, b1, W2, b2, out_vec, out_attn);
}

// Round 11
// 24.125 us; speedup vs baseline: 2.2960x; 2.2960x over previous
//
#include <hip/hip_runtime.h>

#define BATCH   1024
#define NF      64
#define EDIM    64
#define ADIM    32
#define NPAIR   2016        // 64*63/2
#define XSTR    72          // f16 elems/row: 144B rows -> 16B aligned, bank rot 4/row
#define ASTR    68          // As stride: 136B rows -> 8B aligned (b64 reads), 4-way col scatter

typedef _Float16 f16;
typedef f16   f16x2  __attribute__((ext_vector_type(2)));
typedef f16   f16x4  __attribute__((ext_vector_type(4)));
typedef f16   f16x8  __attribute__((ext_vector_type(8)));
typedef float f32x2  __attribute__((ext_vector_type(2)));
typedef float f32x4  __attribute__((ext_vector_type(4)));
typedef float f32x16 __attribute__((ext_vector_type(16)));

__device__ __forceinline__ f16x8 asH(int4 v) {
    union { int4 i; f16x8 h; } u; u.i = v; return u.h;
}
__device__ __forceinline__ f16x2 pkrtz(float a, float b) {
    union { __fp16 __attribute__((ext_vector_type(2))) r; f16x2 h; } u;
    u.r = __builtin_amdgcn_cvt_pkrtz(a, b);
    return u.h;
}

__global__ __launch_bounds__(256, 4) void afm_kernel(
    const float* __restrict__ emb,    // (B, NF, E)
    const float* __restrict__ W1,     // (E, A)
    const float* __restrict__ b1,     // (A)
    const float* __restrict__ W2,     // (A, 1)
    const float* __restrict__ b2,     // (1)
    float* __restrict__ out_vec,      // (B, E)
    float* __restrict__ out_attn)     // (B, NPAIR)
{
    __shared__ __align__(16) f16 xs[NF * XSTR];   // x, f16, [field][e]
    __shared__ __align__(16) f16 Xt[EDIM * XSTR]; // x^T, f16, [e][field]
    __shared__ __align__(16) f16 As[NF * ASTR];   // UNNORMALIZED exp matrix, f16
    // eh: unnormalized exp values (f16, p-indexed, 4032 B). partial (1024 B)
    // aliases its start: all eh reads finish before the red-barrier; partial
    // is written only after it.
    __shared__ __align__(16) char Ubuf[NPAIR * 2];
    f16* eh = (f16*)Ubuf;
    float (*partial)[EDIM] = (float (*)[EDIM])Ubuf;
    __shared__ float red[8];

    const int t    = threadIdx.x;
    const int b    = blockIdx.x;
    const int wid  = t >> 6;
    const int lane = t & 63;
    const int g    = lane >> 4;   // for phase 3 (16x16 fragments)
    const int m16  = lane & 15;
    const int h    = lane >> 5;   // K-half for 32x32 fragments
    const int l32  = lane & 31;
    const int l16  = lane & 15;
    const int hb   = l32 >> 4;    // 16-row within 32-col group

    // ---- stage x into LDS as f16 (row-major; transpose built later) ----
    const float4* xg4 = (const float4*)(emb + (size_t)b * NF * EDIM);
    #pragma unroll
    for (int it = 0; it < 4; ++it) {
        int idx = t + it * 256;
        int f = idx >> 4, e4 = (idx & 15) * 4;
        float4 v = xg4[idx];
        f16x2 p0 = pkrtz(v.x, v.y);
        f16x2 p1 = pkrtz(v.z, v.w);
        f16x4 pk = {p0.x, p0.y, p1.x, p1.y};
        *(f16x4*)&xs[f * XSTR + e4] = pk;
    }

    // ---- W1^T A-fragments for 32x32x16: A[m=adim=l32][k=8h+jj] ----
    f16x8 w1a[4];
    #pragma unroll
    for (int q = 0; q < 4; ++q)
        #pragma unroll
        for (int jj = 0; jj < 8; jj += 2) {
            float fa = W1[(16 * q + 8 * h + jj)     * ADIM + l32];
            float fb = W1[(16 * q + 8 * h + jj + 1) * ADIM + l32];
            f16x2 pk = pkrtz(fa, fb);
            w1a[q][jj] = pk.x; w1a[q][jj + 1] = pk.y;
        }

    // b1/W2 as packed f32x2 pairs in C/D row order: a(r) = (r&3)+8*(r>>2)+4h
    f32x2 b1f2[8], w2f2[8];
    #pragma unroll
    for (int rr = 0; rr < 8; ++rr) {
        int r = 2 * rr;
        int a = (r & 3) + 8 * (r >> 2) + 4 * h;
        b1f2[rr] = (f32x2){b1[a], b1[a + 1]};
        w2f2[rr] = (f32x2){W2[a], W2[a + 1]};
    }
    const float b2s = b2[0];
    __syncthreads();

    // ---- build Xt via read-transpose (conflict-free both sides) ----
    {
        const unsigned short* xsu = (const unsigned short*)xs;
        #pragma unroll
        for (int it = 0; it < 2; ++it) {
            int cid = t + it * 256;
            int e = cid & 63, c = cid >> 6;     // e = lane, c uniform per wave
            unsigned int d[4];
            #pragma unroll
            for (int r2 = 0; r2 < 4; ++r2) {
                unsigned lo = xsu[(8 * c + 2 * r2)     * XSTR + e];
                unsigned hi = xsu[(8 * c + 2 * r2 + 1) * XSTR + e];
                d[r2] = lo | (hi << 16);
            }
            int4 w4 = {(int)d[0], (int)d[1], (int)d[2], (int)d[3]};
            *(int4*)&Xt[e * XSTR + 8 * c] = w4;
        }
    }
    __syncthreads();

    // ---- DPP direction probe: jv registers rotate WITH the data ----
    int probe = __builtin_amdgcn_mov_dpp(l16, 0x124, 0xF, 0xF, false);
    const bool plus4 = (probe == ((l16 + 4) & 15));
    const int  s0r   = plus4 ? (wid + 1) : (wid + 5);

    // ---- phase 1: exp(logit) via 32x32x16 MFMA, register rows + DPP ----
    int4 xi4[4], xj4[4];

    auto LOADX = [&](int row, int4* d) {
        #pragma unroll
        for (int q = 0; q < 4; ++q)
            d[q] = *(const int4*)&xs[row * XSTR + 16 * q + 8 * h];
    };
    auto ROT4D = [&](int4* d, int& jv) {   // rotate data AND its row index
        #pragma unroll
        for (int q = 0; q < 4; ++q) {
            d[q].x = __builtin_amdgcn_mov_dpp(d[q].x, 0x124, 0xF, 0xF, false);
            d[q].y = __builtin_amdgcn_mov_dpp(d[q].y, 0x124, 0xF, 0xF, false);
            d[q].z = __builtin_amdgcn_mov_dpp(d[q].z, 0x124, 0xF, 0xF, false);
            d[q].w = __builtin_amdgcn_mov_dpp(d[q].w, 0x124, 0xF, 0xF, false);
        }
        jv = __builtin_amdgcn_mov_dpp(jv, 0x124, 0xF, 0xF, false);
    };
    auto SUB = [&](const int4* xa, const int4* xb, int iv, int jv) {
        f32x16 acc = {};
        #pragma unroll
        for (int q = 0; q < 4; ++q) {
            f16x8 prod = asH(xa[q]) * asH(xb[q]);   // v_pk_mul_f16 x4
            acc = __builtin_amdgcn_mfma_f32_32x32x16_f16(w1a[q], prod, acc, 0, 0, 0);
        }
        f32x2 tr2 = {0.f, 0.f};
        #pragma unroll
        for (int rr = 0; rr < 8; ++rr) {
            f32x2 a2 = {acc[2 * rr], acc[2 * rr + 1]};
            f32x2 h2 = __builtin_elementwise_max(a2 + b1f2[rr], (f32x2){0.f, 0.f});
            tr2 += h2 * w2f2[rr];
        }
        float tr = tr2.x + tr2.y;
        tr += __shfl_xor(tr, 32);
        // Unnormalized softmax numerator; logits bounded (~|5|) so exp fits
        // f16 (max 65504) with huge headroom. Normalization folded later.
        float ev = __expf(tr + b2s);
        int imin = min(iv, jv), jmax = max(iv, jv);
        int p = ((imin * (127 - imin)) >> 1) + jmax - imin - 1;
        if (lane < 32) {
            f16 ah = (f16)ev;
            eh[p] = ah;
            As[imin * ASTR + jmax] = ah;
            As[jmax * ASTR + imin] = ah;
        }
    };

    LOADX(l32, xi4);
    {   // off-diag (0,1) pattern A
        int jv = 32 + 16 * hb + ((l16 + wid) & 15);
        LOADX(jv, xj4);
        #pragma unroll
        for (int k = 0; k < 4; ++k) {
            SUB(xi4, xj4, l32, jv);
            if (k < 3) ROT4D(xj4, jv);
        }
    }
    {   // off-diag (0,1) pattern B
        int jv = 32 + 16 * (1 - hb) + ((l16 + wid) & 15);
        LOADX(jv, xj4);
        #pragma unroll
        for (int k = 0; k < 4; ++k) {
            SUB(xi4, xj4, l32, jv);
            if (k < 3) ROT4D(xj4, jv);
        }
    }
    {   // diag (0,0) ring
        int jv = 16 * hb + ((l16 + s0r) & 15);
        LOADX(jv, xj4);
        SUB(xi4, xj4, l32, jv);
        ROT4D(xj4, jv);
        SUB(xi4, xj4, l32, jv);
    }
    {   // diag (0,0) cross
        int jv = 16 + ((l16 + wid + 8 * hb) & 15);
        LOADX(l16, xi4);
        LOADX(jv, xj4);
        SUB(xi4, xj4, l16, jv);
        ROT4D(xj4, jv);
        SUB(xi4, xj4, l16, jv);
    }
    {   // diag (1,1) ring
        int jv = 32 + 16 * hb + ((l16 + s0r) & 15);
        LOADX(32 + l32, xi4);
        LOADX(jv, xj4);
        SUB(xi4, xj4, 32 + l32, jv);
        ROT4D(xj4, jv);
        SUB(xi4, xj4, 32 + l32, jv);
    }
    {   // diag (1,1) cross
        int jv = 48 + ((l16 + wid + 8 * hb) & 15);
        LOADX(32 + l16, xi4);
        LOADX(jv, xj4);
        SUB(xi4, xj4, 32 + l16, jv);
        ROT4D(xj4, jv);
        SUB(xi4, xj4, 32 + l16, jv);
    }
    if (t < NF) As[t * ASTR + t] = (f16)0.f;   // zero diagonal (i != j in SUBs)
    __syncthreads();

    // ---- phase 2: SUM reduction over f16 exp values ----
    float lv[8];
    #pragma unroll
    for (int k = 0; k < 8; ++k) {
        int p = t + 256 * k;
        lv[k] = (p < NPAIR) ? (float)eh[p] : 0.f;
    }
    float sw = 0.f;
    #pragma unroll
    for (int k = 0; k < 8; ++k) sw += lv[k];
    #pragma unroll
    for (int off = 32; off; off >>= 1) sw += __shfl_xor(sw, off);
    if (lane == 0) red[wid] = sw;
    __syncthreads();      // after this barrier eh is dead; partial may alias
    const float inv = 1.0f / (red[0] + red[1] + red[2] + red[3]);

    #pragma unroll
    for (int k = 0; k < 8; ++k) {
        int p = t + 256 * k;
        if (p < NPAIR) out_attn[(size_t)b * NPAIR + p] = lv[k] * inv;
    }

    // ---- phase 3: Y = E @ X via MFMA; out[e] = 0.5*inv * sum_i X[i,e] Y[i,e] ----
    const int itile = wid;          // each wave owns 16 rows of E
    const f16* arow = &As[(itile * 16 + m16) * ASTR];
    f16x4 afa0 = *(const f16x4*)(arow + 8 * g);
    f16x4 afb0 = *(const f16x4*)(arow + 8 * g + 4);
    f16x4 afa1 = *(const f16x4*)(arow + 32 + 8 * g);
    f16x4 afb1 = *(const f16x4*)(arow + 32 + 8 * g + 4);
    f16x8 af0, af1;
    #pragma unroll
    for (int j = 0; j < 4; ++j) {
        af0[j] = afa0[j]; af0[4 + j] = afb0[j];
        af1[j] = afa1[j]; af1[4 + j] = afb1[j];
    }

    f32x4 yacc[4];
    #pragma unroll
    for (int et = 0; et < 4; ++et) yacc[et] = (f32x4){0.f, 0.f, 0.f, 0.f};
    #pragma unroll
    for (int et = 0; et < 4; ++et) {
        const f16* xtr = &Xt[(et * 16 + m16) * XSTR];
        f16x8 bf0 = *(const f16x8*)(xtr + 8 * g);
        f16x8 bf1 = *(const f16x8*)(xtr + 32 + 8 * g);
        yacc[et] = __builtin_amdgcn_mfma_f32_16x16x32_f16(af0, bf0, yacc[et], 0, 0, 0);
        yacc[et] = __builtin_amdgcn_mfma_f32_16x16x32_f16(af1, bf1, yacc[et], 0, 0, 0);
    }

    #pragma unroll
    for (int et = 0; et < 4; ++et) {
        float v = 0.f;
        #pragma unroll
        for (int r = 0; r < 4; ++r) {
            int i = itile * 16 + 4 * g + r;
            int e = et * 16 + m16;
            v = fmaf((float)xs[i * XSTR + e], yacc[et][r], v);
        }
        v += __shfl_xor(v, 16);
        v += __shfl_xor(v, 32);
        if (g == 0) partial[wid][et * 16 + m16] = v;
    }
    __syncthreads();
    if (t < EDIM)
        out_vec[(size_t)b * EDIM + t] = 0.5f * inv *
            (partial[0][t] + partial[1][t] + partial[2][t] + partial[3][t]);
}

extern "C" void kernel_launch(void* const* d_in, const int* in_sizes, int n_in,
                              void* d_out, int out_size, void* d_ws, size_t ws_size,
                              hipStream_t stream) {
    const float* emb = (const float*)d_in[0];
    const float* W1  = (const float*)d_in[1];
    const float* b1  = (const float*)d_in[2];
    const float* W2  = (const float*)d_in[3];
    const float* b2  = (const float*)d_in[4];
    float* out_vec  = (float*)d_out;                        // (B, E)
    float* out_attn = (float*)d_out + (size_t)BATCH * EDIM; // (B, NPAIR)

    afm_kernel<<<BATCH, 256, 0, stream>>>(emb, W1, b1, W2, b2, out_vec, out_attn);
}

// Round 12
// 23.837 us; speedup vs baseline: 2.3237x; 1.0121x over previous
//
#include <hip/hip_runtime.h>

#define BATCH   1024
#define NF      64
#define EDIM    64
#define ADIM    32
#define NPAIR   2016        // 64*63/2
#define XSTR    72          // f16 elems/row: 144B rows -> 16B aligned, bank rot 4/row
#define ASTR    68          // As stride: 136B rows -> 8B aligned (b64 reads), 4-way col scatter

typedef _Float16 f16;
typedef f16   f16x2  __attribute__((ext_vector_type(2)));
typedef f16   f16x4  __attribute__((ext_vector_type(4)));
typedef f16   f16x8  __attribute__((ext_vector_type(8)));
typedef float f32x2  __attribute__((ext_vector_type(2)));
typedef float f32x4  __attribute__((ext_vector_type(4)));
typedef float f32x16 __attribute__((ext_vector_type(16)));

__device__ __forceinline__ f16x8 asH(int4 v) {
    union { int4 i; f16x8 h; } u; u.i = v; return u.h;
}
__device__ __forceinline__ f16x2 pkrtz(float a, float b) {
    union { __fp16 __attribute__((ext_vector_type(2))) r; f16x2 h; } u;
    u.r = __builtin_amdgcn_cvt_pkrtz(a, b);
    return u.h;
}

__global__ __launch_bounds__(256, 4) void afm_kernel(
    const float* __restrict__ emb,    // (B, NF, E)
    const float* __restrict__ W1,     // (E, A)
    const float* __restrict__ b1,     // (A)
    const float* __restrict__ W2,     // (A, 1)
    const float* __restrict__ b2,     // (1)
    float* __restrict__ out_vec,      // (B, E)
    float* __restrict__ out_attn)     // (B, NPAIR)
{
    __shared__ __align__(16) f16 xs[NF * XSTR];   // x, f16, [field][e]
    __shared__ __align__(16) f16 Xt[EDIM * XSTR]; // x^T, f16, [e][field]
    __shared__ __align__(16) f16 As[NF * ASTR];   // UNNORMALIZED exp matrix, f16
    // eh: unnormalized exp values (f16, p-indexed, 4032 B). partial (1024 B)
    // aliases its start: all eh reads finish before the red-barrier; partial
    // is written only after it.
    __shared__ __align__(16) char Ubuf[NPAIR * 2];
    f16* eh = (f16*)Ubuf;
    float (*partial)[EDIM] = (float (*)[EDIM])Ubuf;
    __shared__ float red[8];

    const int t    = threadIdx.x;
    const int b    = blockIdx.x;
    const int wid  = t >> 6;
    const int lane = t & 63;
    const int g    = lane >> 4;   // for phase 3 (16x16 fragments)
    const int m16  = lane & 15;
    const int h    = lane >> 5;   // K-half for 32x32 fragments
    const int l32  = lane & 31;
    const int l16  = lane & 15;
    const int hb   = l32 >> 4;    // 16-row within 32-col group

    // ---- stage x into LDS as f16 (row-major; transpose built later) ----
    const float4* xg4 = (const float4*)(emb + (size_t)b * NF * EDIM);
    #pragma unroll
    for (int it = 0; it < 4; ++it) {
        int idx = t + it * 256;
        int f = idx >> 4, e4 = (idx & 15) * 4;
        float4 v = xg4[idx];
        f16x2 p0 = pkrtz(v.x, v.y);
        f16x2 p1 = pkrtz(v.z, v.w);
        f16x4 pk = {p0.x, p0.y, p1.x, p1.y};
        *(f16x4*)&xs[f * XSTR + e4] = pk;
    }

    // ---- W1^T A-fragments for 32x32x16: A[m=adim=l32][k=8h+jj] ----
    f16x8 w1a[4];
    #pragma unroll
    for (int q = 0; q < 4; ++q)
        #pragma unroll
        for (int jj = 0; jj < 8; jj += 2) {
            float fa = W1[(16 * q + 8 * h + jj)     * ADIM + l32];
            float fb = W1[(16 * q + 8 * h + jj + 1) * ADIM + l32];
            f16x2 pk = pkrtz(fa, fb);
            w1a[q][jj] = pk.x; w1a[q][jj + 1] = pk.y;
        }

    // b1 as MFMA C-init vector (C/D row order a(r) = (r&3)+8*(r>>2)+4h);
    // W2 as packed f32x2 pairs (even r: a(r+1) = a(r)+1).
    f32x16 b1acc;
    #pragma unroll
    for (int r = 0; r < 16; ++r) b1acc[r] = b1[(r & 3) + 8 * (r >> 2) + 4 * h];
    f32x2 w2f2[8];
    #pragma unroll
    for (int rr = 0; rr < 8; ++rr) {
        int a = ((2 * rr) & 3) + 8 * ((2 * rr) >> 2) + 4 * h;
        w2f2[rr] = (f32x2){W2[a], W2[a + 1]};
    }
    // b2 dropped: softmax is shift-invariant; exp(b2) cancels in normalization
    // for BOTH outputs (attn = ev/sum, out_vec scaled by inv).
    __syncthreads();

    // ---- build Xt via read-transpose (no barrier after: phase 1 reads only
    // xs; Xt's first read (phase 3) is two barriers downstream) ----
    {
        const unsigned short* xsu = (const unsigned short*)xs;
        #pragma unroll
        for (int it = 0; it < 2; ++it) {
            int cid = t + it * 256;
            int e = cid & 63, c = cid >> 6;     // e = lane, c uniform per wave
            unsigned int d[4];
            #pragma unroll
            for (int r2 = 0; r2 < 4; ++r2) {
                unsigned lo = xsu[(8 * c + 2 * r2)     * XSTR + e];
                unsigned hi = xsu[(8 * c + 2 * r2 + 1) * XSTR + e];
                d[r2] = lo | (hi << 16);
            }
            int4 w4 = {(int)d[0], (int)d[1], (int)d[2], (int)d[3]};
            *(int4*)&Xt[e * XSTR + 8 * c] = w4;
        }
    }

    // ---- phase 1: exp(logit) via 32x32x16 MFMA, direct per-SUB LDS loads ----
    const f32x16 zacc = {};
    int4 xi4[4], xj4[4];

    auto LOADX = [&](int row, int4* d) {
        #pragma unroll
        for (int q = 0; q < 4; ++q)
            d[q] = *(const int4*)&xs[row * XSTR + 16 * q + 8 * h];
    };
    auto SUBX = [&](const int4* xa, const int4* xb, int iv, int jv) {
        f16x8 p0 = asH(xa[0]) * asH(xb[0]);   // v_pk_mul_f16 x4 each
        f16x8 p1 = asH(xa[1]) * asH(xb[1]);
        f16x8 p2 = asH(xa[2]) * asH(xb[2]);
        f16x8 p3 = asH(xa[3]) * asH(xb[3]);
        // two independent MFMA chains (halved dep latency); b1 folded into
        // chain-A's C-init (D != C, so no register copies).
        f32x16 accA = __builtin_amdgcn_mfma_f32_32x32x16_f16(w1a[0], p0, b1acc, 0, 0, 0);
        f32x16 accB = __builtin_amdgcn_mfma_f32_32x32x16_f16(w1a[2], p2, zacc, 0, 0, 0);
        accA = __builtin_amdgcn_mfma_f32_32x32x16_f16(w1a[1], p1, accA, 0, 0, 0);
        accB = __builtin_amdgcn_mfma_f32_32x32x16_f16(w1a[3], p3, accB, 0, 0, 0);
        f32x2 tr2 = {0.f, 0.f};
        #pragma unroll
        for (int rr = 0; rr < 8; ++rr) {
            f32x2 a2 = {accA[2 * rr] + accB[2 * rr],
                        accA[2 * rr + 1] + accB[2 * rr + 1]};
            f32x2 h2 = __builtin_elementwise_max(a2, (f32x2){0.f, 0.f});
            tr2 += h2 * w2f2[rr];
        }
        float tr = tr2.x + tr2.y;
        tr += __shfl_xor(tr, 32);
        float ev = __expf(tr);                // unnormalized numerator
        int imin = min(iv, jv), jmax = max(iv, jv);
        int p = ((imin * (127 - imin)) >> 1) + jmax - imin - 1;
        if (lane < 32) {
            f16 ah = (f16)ev;
            eh[p] = ah;
            As[imin * ASTR + jmax] = ah;
            As[jmax * ASTR + imin] = ah;
        }
    };

    LOADX(l32, xi4);
    #pragma unroll
    for (int k = 0; k < 4; ++k) {   // off-diag (0,1) pattern A
        int jv = 32 + 16 * hb + ((l16 + wid + 4 * k) & 15);
        LOADX(jv, xj4);
        SUBX(xi4, xj4, l32, jv);
    }
    #pragma unroll
    for (int k = 0; k < 4; ++k) {   // off-diag (0,1) pattern B
        int jv = 32 + 16 * (1 - hb) + ((l16 + wid + 4 * k) & 15);
        LOADX(jv, xj4);
        SUBX(xi4, xj4, l32, jv);
    }
    #pragma unroll
    for (int k = 0; k < 2; ++k) {   // diag (0,0) ring: s = wid+1, wid+5 (1..8)
        int jv = 16 * hb + ((l16 + wid + 1 + 4 * k) & 15);
        LOADX(jv, xj4);
        SUBX(xi4, xj4, l32, jv);
    }
    LOADX(l16, xi4);
    #pragma unroll
    for (int k = 0; k < 2; ++k) {   // diag (0,0) cross
        int jv = 16 + ((l16 + wid + 8 * hb + 4 * k) & 15);
        LOADX(jv, xj4);
        SUBX(xi4, xj4, l16, jv);
    }
    LOADX(32 + l32, xi4);
    #pragma unroll
    for (int k = 0; k < 2; ++k) {   // diag (1,1) ring
        int jv = 32 + 16 * hb + ((l16 + wid + 1 + 4 * k) & 15);
        LOADX(jv, xj4);
        SUBX(xi4, xj4, 32 + l32, jv);
    }
    LOADX(32 + l16, xi4);
    #pragma unroll
    for (int k = 0; k < 2; ++k) {   // diag (1,1) cross
        int jv = 48 + ((l16 + wid + 8 * hb + 4 * k) & 15);
        LOADX(jv, xj4);
        SUBX(xi4, xj4, 32 + l16, jv);
    }
    if (t < NF) As[t * ASTR + t] = (f16)0.f;   // zero diagonal (i != j in SUBs)
    __syncthreads();

    // ---- phase 2: SUM reduction over f16 exp values ----
    float lv[8];
    #pragma unroll
    for (int k = 0; k < 8; ++k) {
        int p = t + 256 * k;
        lv[k] = (p < NPAIR) ? (float)eh[p] : 0.f;
    }
    float sw = 0.f;
    #pragma unroll
    for (int k = 0; k < 8; ++k) sw += lv[k];
    #pragma unroll
    for (int off = 32; off; off >>= 1) sw += __shfl_xor(sw, off);
    if (lane == 0) red[wid] = sw;
    __syncthreads();      // after this barrier eh is dead; partial may alias
    const float inv = 1.0f / (red[0] + red[1] + red[2] + red[3]);

    #pragma unroll
    for (int k = 0; k < 8; ++k) {
        int p = t + 256 * k;
        if (p < NPAIR) out_attn[(size_t)b * NPAIR + p] = lv[k] * inv;
    }

    // ---- phase 3: Y = E @ X via MFMA; out[e] = 0.5*inv * sum_i X[i,e] Y[i,e] ----
    const int itile = wid;          // each wave owns 16 rows of E
    const f16* arow = &As[(itile * 16 + m16) * ASTR];
    f16x4 afa0 = *(const f16x4*)(arow + 8 * g);
    f16x4 afb0 = *(const f16x4*)(arow + 8 * g + 4);
    f16x4 afa1 = *(const f16x4*)(arow + 32 + 8 * g);
    f16x4 afb1 = *(const f16x4*)(arow + 32 + 8 * g + 4);
    f16x8 af0, af1;
    #pragma unroll
    for (int j = 0; j < 4; ++j) {
        af0[j] = afa0[j]; af0[4 + j] = afb0[j];
        af1[j] = afa1[j]; af1[4 + j] = afb1[j];
    }

    f32x4 yacc[4];
    #pragma unroll
    for (int et = 0; et < 4; ++et) yacc[et] = (f32x4){0.f, 0.f, 0.f, 0.f};
    #pragma unroll
    for (int et = 0; et < 4; ++et) {
        const f16* xtr = &Xt[(et * 16 + m16) * XSTR];
        f16x8 bf0 = *(const f16x8*)(xtr + 8 * g);
        f16x8 bf1 = *(const f16x8*)(xtr + 32 + 8 * g);
        yacc[et] = __builtin_amdgcn_mfma_f32_16x16x32_f16(af0, bf0, yacc[et], 0, 0, 0);
        yacc[et] = __builtin_amdgcn_mfma_f32_16x16x32_f16(af1, bf1, yacc[et], 0, 0, 0);
    }

    #pragma unroll
    for (int et = 0; et < 4; ++et) {
        float v = 0.f;
        #pragma unroll
        for (int r = 0; r < 4; ++r) {
            int i = itile * 16 + 4 * g + r;
            int e = et * 16 + m16;
            v = fmaf((float)xs[i * XSTR + e], yacc[et][r], v);
        }
        v += __shfl_xor(v, 16);
        v += __shfl_xor(v, 32);
        if (g == 0) partial[wid][et * 16 + m16] = v;
    }
    __syncthreads();
    if (t < EDIM)
        out_vec[(size_t)b * EDIM + t] = 0.5f * inv *
            (partial[0][t] + partial[1][t] + partial[2][t] + partial[3][t]);
}

extern "C" void kernel_launch(void* const* d_in, const int* in_sizes, int n_in,
                              void* d_out, int out_size, void* d_ws, size_t ws_size,
                              hipStream_t stream) {
    const float* emb = (const float*)d_in[0];
    const float* W1  = (const float*)d_in[1];
    const float* b1  = (const float*)d_in[2];
    const float* W2  = (const float*)d_in[3];
    const float* b2  = (const float*)d_in[4];
    (void)b2;  // softmax shift-invariance: b2 cancels in both outputs
    float* out_vec  = (float*)d_out;                        // (B, E)
    float* out_attn = (float*)d_out + (size_t)BATCH * EDIM; // (B, NPAIR)

    afm_kernel<<<BATCH, 256, 0, stream>>>(emb, W1, b1, W2, b2, out_vec, out_attn);
}

// Round 14
// 23.614 us; speedup vs baseline: 2.3457x; 1.0095x over previous
//
#include <hip/hip_runtime.h>

#define BATCH   1024
#define NF      64
#define EDIM    64
#define ADIM    32
#define NPAIR   2016        // 64*63/2
#define XSTR    72          // f16 elems/row: 144B rows -> 16B aligned, bank rot 4/row
#define ASTR    68          // As stride: 136B rows -> 8B aligned (b64 reads), 4-way col scatter

typedef _Float16 f16;
typedef f16   f16x2  __attribute__((ext_vector_type(2)));
typedef f16   f16x4  __attribute__((ext_vector_type(4)));
typedef f16   f16x8  __attribute__((ext_vector_type(8)));
typedef float f32x2  __attribute__((ext_vector_type(2)));
typedef float f32x4  __attribute__((ext_vector_type(4)));
typedef float f32x16 __attribute__((ext_vector_type(16)));

__device__ __forceinline__ f16x8 asH(int4 v) {
    union { int4 i; f16x8 h; } u; u.i = v; return u.h;
}
__device__ __forceinline__ f16x2 pkrtz(float a, float b) {
    union { __fp16 __attribute__((ext_vector_type(2))) r; f16x2 h; } u;
    u.r = __builtin_amdgcn_cvt_pkrtz(a, b);
    return u.h;
}

__global__ __launch_bounds__(256, 4) void afm_kernel(
    const float* __restrict__ emb,    // (B, NF, E)
    const float* __restrict__ W1,     // (E, A)
    const float* __restrict__ b1,     // (A)
    const float* __restrict__ W2,     // (A, 1)
    const float* __restrict__ b2,     // (1)
    float* __restrict__ out_vec,      // (B, E)
    float* __restrict__ out_attn)     // (B, NPAIR)
{
    __shared__ __align__(16) f16 xs[NF * XSTR];   // x, f16, [field][e]
    __shared__ __align__(16) f16 Xt[EDIM * XSTR]; // x^T, f16, [e][field]
    __shared__ __align__(16) f16 As[NF * ASTR];   // UNNORMALIZED exp matrix, f16
    // eh: unnormalized exp values (f16, p-indexed, 4032 B). partial (1024 B)
    // aliases its start: all eh reads finish before the red-barrier; partial
    // is written only after it.
    __shared__ __align__(16) char Ubuf[NPAIR * 2];
    f16* eh = (f16*)Ubuf;
    float (*partial)[EDIM] = (float (*)[EDIM])Ubuf;
    __shared__ float red[8];

    const int t    = threadIdx.x;
    const int b    = blockIdx.x;
    const int wid  = t >> 6;
    const int lane = t & 63;
    const int g    = lane >> 4;   // for phase 3 (16x16 fragments)
    const int m16  = lane & 15;
    const int h    = lane >> 5;   // K-half for 32x32 fragments
    const int l32  = lane & 31;
    const int l16  = lane & 15;
    const int hb   = l32 >> 4;    // 16-row within 32-col group

    // ---- stage x into LDS as f16 (nontemporal: streamed once, no reuse) ----
    const f32x4* xg4 = (const f32x4*)(emb + (size_t)b * NF * EDIM);
    #pragma unroll
    for (int it = 0; it < 4; ++it) {
        int idx = t + it * 256;
        int f = idx >> 4, e4 = (idx & 15) * 4;
        f32x4 v = __builtin_nontemporal_load(xg4 + idx);
        f16x2 p0 = pkrtz(v[0], v[1]);
        f16x2 p1 = pkrtz(v[2], v[3]);
        f16x4 pk = {p0.x, p0.y, p1.x, p1.y};
        *(f16x4*)&xs[f * XSTR + e4] = pk;
    }

    // ---- W1^T A-fragments for 32x32x16: A[m=adim=l32][k=8h+jj] ----
    f16x8 w1a[4];
    #pragma unroll
    for (int q = 0; q < 4; ++q)
        #pragma unroll
        for (int jj = 0; jj < 8; jj += 2) {
            float fa = W1[(16 * q + 8 * h + jj)     * ADIM + l32];
            float fb = W1[(16 * q + 8 * h + jj + 1) * ADIM + l32];
            f16x2 pk = pkrtz(fa, fb);
            w1a[q][jj] = pk.x; w1a[q][jj + 1] = pk.y;
        }

    // b1 as MFMA C-init vector (C/D row order a(r) = (r&3)+8*(r>>2)+4h);
    // W2 as packed f32x2 pairs (even r: a(r+1) = a(r)+1).
    f32x16 b1acc;
    #pragma unroll
    for (int r = 0; r < 16; ++r) b1acc[r] = b1[(r & 3) + 8 * (r >> 2) + 4 * h];
    f32x2 w2f2[8];
    #pragma unroll
    for (int rr = 0; rr < 8; ++rr) {
        int a = ((2 * rr) & 3) + 8 * ((2 * rr) >> 2) + 4 * h;
        w2f2[rr] = (f32x2){W2[a], W2[a + 1]};
    }
    // b2 dropped: softmax is shift-invariant; exp(b2) cancels in normalization
    __syncthreads();

    // ---- build Xt via read-transpose (no barrier after: phase 1 reads only
    // xs; Xt's first read (phase 3) is two barriers downstream) ----
    {
        const unsigned short* xsu = (const unsigned short*)xs;
        #pragma unroll
        for (int it = 0; it < 2; ++it) {
            int cid = t + it * 256;
            int e = cid & 63, c = cid >> 6;     // e = lane, c uniform per wave
            unsigned int d[4];
            #pragma unroll
            for (int r2 = 0; r2 < 4; ++r2) {
                unsigned lo = xsu[(8 * c + 2 * r2)     * XSTR + e];
                unsigned hi = xsu[(8 * c + 2 * r2 + 1) * XSTR + e];
                d[r2] = lo | (hi << 16);
            }
            int4 w4 = {(int)d[0], (int)d[1], (int)d[2], (int)d[3]};
            *(int4*)&Xt[e * XSTR + 8 * c] = w4;
        }
    }

    // ---- phase 1: exp(logit) via 32x32x16 MFMA, direct per-SUB LDS loads ----
    const f32x16 zacc = {};
    int4 xi4[4], xj4[4];

    auto LOADX = [&](int row, int4* d) {
        #pragma unroll
        for (int q = 0; q < 4; ++q)
            d[q] = *(const int4*)&xs[row * XSTR + 16 * q + 8 * h];
    };
    auto SUBX = [&](const int4* xa, const int4* xb, int iv, int jv) {
        f16x8 p0 = asH(xa[0]) * asH(xb[0]);   // v_pk_mul_f16 x4 each
        f16x8 p1 = asH(xa[1]) * asH(xb[1]);
        f16x8 p2 = asH(xa[2]) * asH(xb[2]);
        f16x8 p3 = asH(xa[3]) * asH(xb[3]);
        // two independent MFMA chains (halved dep latency); b1 folded into
        // chain-A's C-init (D != C, so no register copies).
        f32x16 accA = __builtin_amdgcn_mfma_f32_32x32x16_f16(w1a[0], p0, b1acc, 0, 0, 0);
        f32x16 accB = __builtin_amdgcn_mfma_f32_32x32x16_f16(w1a[2], p2, zacc, 0, 0, 0);
        accA = __builtin_amdgcn_mfma_f32_32x32x16_f16(w1a[1], p1, accA, 0, 0, 0);
        accB = __builtin_amdgcn_mfma_f32_32x32x16_f16(w1a[3], p3, accB, 0, 0, 0);
        f32x2 tr2 = {0.f, 0.f};
        #pragma unroll
        for (int rr = 0; rr < 8; ++rr) {
            f32x2 a2 = {accA[2 * rr] + accB[2 * rr],
                        accA[2 * rr + 1] + accB[2 * rr + 1]};
            f32x2 h2 = __builtin_elementwise_max(a2, (f32x2){0.f, 0.f});
            tr2 += h2 * w2f2[rr];
        }
        float tr = tr2.x + tr2.y;
        tr += __shfl_xor(tr, 32);
        float ev = __expf(tr);                // unnormalized numerator
        int imin = min(iv, jv), jmax = max(iv, jv);
        int p = ((imin * (127 - imin)) >> 1) + jmax - imin - 1;
        if (lane < 32) {
            f16 ah = (f16)ev;
            eh[p] = ah;
            As[imin * ASTR + jmax] = ah;
            As[jmax * ASTR + imin] = ah;
        }
    };

    LOADX(l32, xi4);
    #pragma unroll
    for (int k = 0; k < 4; ++k) {   // off-diag (0,1) pattern A
        int jv = 32 + 16 * hb + ((l16 + wid + 4 * k) & 15);
        LOADX(jv, xj4);
        SUBX(xi4, xj4, l32, jv);
    }
    #pragma unroll
    for (int k = 0; k < 4; ++k) {   // off-diag (0,1) pattern B
        int jv = 32 + 16 * (1 - hb) + ((l16 + wid + 4 * k) & 15);
        LOADX(jv, xj4);
        SUBX(xi4, xj4, l32, jv);
    }
    #pragma unroll
    for (int k = 0; k < 2; ++k) {   // diag (0,0) ring: s = wid+1, wid+5 (1..8)
        int jv = 16 * hb + ((l16 + wid + 1 + 4 * k) & 15);
        LOADX(jv, xj4);
        SUBX(xi4, xj4, l32, jv);
    }
    LOADX(l16, xi4);
    #pragma unroll
    for (int k = 0; k < 2; ++k) {   // diag (0,0) cross
        int jv = 16 + ((l16 + wid + 8 * hb + 4 * k) & 15);
        LOADX(jv, xj4);
        SUBX(xi4, xj4, l16, jv);
    }
    LOADX(32 + l32, xi4);
    #pragma unroll
    for (int k = 0; k < 2; ++k) {   // diag (1,1) ring
        int jv = 32 + 16 * hb + ((l16 + wid + 1 + 4 * k) & 15);
        LOADX(jv, xj4);
        SUBX(xi4, xj4, 32 + l32, jv);
    }
    LOADX(32 + l16, xi4);
    #pragma unroll
    for (int k = 0; k < 2; ++k) {   // diag (1,1) cross
        int jv = 48 + ((l16 + wid + 8 * hb + 4 * k) & 15);
        LOADX(jv, xj4);
        SUBX(xi4, xj4, 32 + l16, jv);
    }
    if (t < NF) As[t * ASTR + t] = (f16)0.f;   // zero diagonal (i != j in SUBs)
    __syncthreads();

    // ---- phase 2: SUM reduction; thread t owns p in [8t, 8t+8) ----
    float lv[8];
    float sw = 0.f;
    if (t < NPAIR / 8) {
        f16x8 e8 = *(const f16x8*)&eh[8 * t];   // one ds_read_b128
        #pragma unroll
        for (int k = 0; k < 8; ++k) { lv[k] = (float)e8[k]; sw += lv[k]; }
    }
    #pragma unroll
    for (int off = 32; off; off >>= 1) sw += __shfl_xor(sw, off);
    if (lane == 0) red[wid] = sw;
    __syncthreads();      // after this barrier eh is dead; partial may alias
    const float inv = 1.0f / (red[0] + red[1] + red[2] + red[3]);

    if (t < NPAIR / 8) {
        f32x4 o0 = {lv[0] * inv, lv[1] * inv, lv[2] * inv, lv[3] * inv};
        f32x4 o1 = {lv[4] * inv, lv[5] * inv, lv[6] * inv, lv[7] * inv};
        f32x4* dst = (f32x4*)(out_attn + (size_t)b * NPAIR + 8 * t);
        __builtin_nontemporal_store(o0, dst);       // skip RFO on write miss
        __builtin_nontemporal_store(o1, dst + 1);
    }

    // ---- phase 3: Y = E @ X via MFMA; out[e] = 0.5*inv * sum_i X[i,e] Y[i,e] ----
    const int itile = wid;          // each wave owns 16 rows of E
    const f16* arow = &As[(itile * 16 + m16) * ASTR];
    f16x4 afa0 = *(const f16x4*)(arow + 8 * g);
    f16x4 afb0 = *(const f16x4*)(arow + 8 * g + 4);
    f16x4 afa1 = *(const f16x4*)(arow + 32 + 8 * g);
    f16x4 afb1 = *(const f16x4*)(arow + 32 + 8 * g + 4);
    f16x8 af0, af1;
    #pragma unroll
    for (int j = 0; j < 4; ++j) {
        af0[j] = afa0[j]; af0[4 + j] = afb0[j];
        af1[j] = afa1[j]; af1[4 + j] = afb1[j];
    }

    f32x4 yacc[4];
    #pragma unroll
    for (int et = 0; et < 4; ++et) yacc[et] = (f32x4){0.f, 0.f, 0.f, 0.f};
    #pragma unroll
    for (int et = 0; et < 4; ++et) {
        const f16* xtr = &Xt[(et * 16 + m16) * XSTR];
        f16x8 bf0 = *(const f16x8*)(xtr + 8 * g);
        f16x8 bf1 = *(const f16x8*)(xtr + 32 + 8 * g);
        yacc[et] = __builtin_amdgcn_mfma_f32_16x16x32_f16(af0, bf0, yacc[et], 0, 0, 0);
        yacc[et] = __builtin_amdgcn_mfma_f32_16x16x32_f16(af1, bf1, yacc[et], 0, 0, 0);
    }

    #pragma unroll
    for (int et = 0; et < 4; ++et) {
        float v = 0.f;
        #pragma unroll
        for (int r = 0; r < 4; ++r) {
            int i = itile * 16 + 4 * g + r;
            int e = et * 16 + m16;
            v = fmaf((float)xs[i * XSTR + e], yacc[et][r], v);
        }
        v += __shfl_xor(v, 16);
        v += __shfl_xor(v, 32);
        if (g == 0) partial[wid][et * 16 + m16] = v;
    }
    __syncthreads();
    if (t < EDIM) {
        float o = 0.5f * inv *
            (partial[0][t] + partial[1][t] + partial[2][t] + partial[3][t]);
        __builtin_nontemporal_store(o, out_vec + (size_t)b * EDIM + t);
    }
}

extern "C" void kernel_launch(void* const* d_in, const int* in_sizes, int n_in,
                              void* d_out, int out_size, void* d_ws, size_t ws_size,
                              hipStream_t stream) {
    const float* emb = (const float*)d_in[0];
    const float* W1  = (const float*)d_in[1];
    const float* b1  = (const float*)d_in[2];
    const float* W2  = (const float*)d_in[3];
    const float* b2  = (const float*)d_in[4];
    (void)b2;  // softmax shift-invariance: b2 cancels in both outputs
    float* out_vec  = (float*)d_out;                        // (B, E)
    float* out_attn = (float*)d_out + (size_t)BATCH * EDIM; // (B, NPAIR)

    afm_kernel<<<BATCH, 256, 0, stream>>>(emb, W1, b1, W2, b2, out_vec, out_attn);
}